// Round 12
// baseline (164.001 us; speedup 1.0000x reference)
//
#include <hip/hip_runtime.h>
#include <math.h>

#define NN 2048      // nodes
#define HH 6         // heads
#define HD 768       // H*D
#define NA 32        // agents/scene
#define NB 64        // scenes

typedef __bf16 bf16x8 __attribute__((ext_vector_type(8)));
typedef float  f32x4  __attribute__((ext_vector_type(4)));

// split f into bf16 hi + bf16 lo (truncation; hi+lo ~ 2^-17 relative)
__device__ __forceinline__ void split2(float f, ushort& h, ushort& l) {
    const uint u = __float_as_uint(f);
    h = (ushort)(u >> 16);
    const float hf = __uint_as_float((uint)h << 16);
    l = (ushort)(__float_as_uint(f - hf) >> 16);
}

__device__ __forceinline__ bf16x8 pack8(const ushort* s) {
    uint4 u;
    u.x = (uint)s[0] | ((uint)s[1] << 16);
    u.y = (uint)s[2] | ((uint)s[3] << 16);
    u.z = (uint)s[4] | ((uint)s[5] << 16);
    u.w = (uint)s[6] | ((uint)s[7] << 16);
    return *(bf16x8*)&u;
}

// load 8 fp32, apply LN (gamma/beta), split to bf16 hi/lo fragments
__device__ __forceinline__ void ln8_split(
    const float* __restrict__ x, float mu, float rs,
    const float* __restrict__ g, const float* __restrict__ b,
    bf16x8& hi, bf16x8& lo)
{
    const float4 x0 = *(const float4*)x;
    const float4 x1 = *(const float4*)(x + 4);
    const float4 g0 = *(const float4*)g;
    const float4 g1 = *(const float4*)(g + 4);
    const float4 b0 = *(const float4*)b;
    const float4 b1 = *(const float4*)(b + 4);
    ushort hh[8], ll[8];
    float v;
    v = (x0.x - mu) * rs * g0.x + b0.x; split2(v, hh[0], ll[0]);
    v = (x0.y - mu) * rs * g0.y + b0.y; split2(v, hh[1], ll[1]);
    v = (x0.z - mu) * rs * g0.z + b0.z; split2(v, hh[2], ll[2]);
    v = (x0.w - mu) * rs * g0.w + b0.w; split2(v, hh[3], ll[3]);
    v = (x1.x - mu) * rs * g1.x + b1.x; split2(v, hh[4], ll[4]);
    v = (x1.y - mu) * rs * g1.y + b1.y; split2(v, hh[5], ll[5]);
    v = (x1.z - mu) * rs * g1.z + b1.z; split2(v, hh[6], ll[6]);
    v = (x1.w - mu) * rs * g1.w + b1.w; split2(v, hh[7], ll[7]);
    hi = pack8(hh); lo = pack8(ll);
}

// ---------------------------------------------------------------------------
// K0: split agents / Wq / Wk / Wv / Wo1 / Wo2 / W1 / W2 into bf16 hi+lo.
// ---------------------------------------------------------------------------
__global__ __launch_bounds__(256) void split_kernel(
    const float* __restrict__ agents, const float* __restrict__ Wq,
    const float* __restrict__ Wk, const float* __restrict__ Wv,
    const float* __restrict__ Wo1, const float* __restrict__ Wo2,
    const float* __restrict__ W1, const float* __restrict__ W2,
    ushort* __restrict__ Ahi, ushort* __restrict__ Alo,
    ushort* __restrict__ Whi, ushort* __restrict__ Wlo,
    ushort* __restrict__ Wo1hi, ushort* __restrict__ Wo1lo,
    ushort* __restrict__ Wo2hi, ushort* __restrict__ Wo2lo,
    ushort* __restrict__ W1hi, ushort* __restrict__ W1lo,
    ushort* __restrict__ W2hi, ushort* __restrict__ W2lo)
{
    const int y = blockIdx.y;
    const float* src;
    ushort *dh, *dl;
    int n4;
    switch (y) {
        case 0:  src = agents; dh = Ahi;   dl = Alo;   n4 = NN * 128 / 4;  break;
        case 1:  src = Wq;  dh = Whi;                dl = Wlo;                n4 = 768*128/4; break;
        case 2:  src = Wk;  dh = Whi + 768*128;      dl = Wlo + 768*128;      n4 = 768*128/4; break;
        case 3:  src = Wv;  dh = Whi + 2*768*128;    dl = Wlo + 2*768*128;    n4 = 768*128/4; break;
        case 4:  src = Wo1; dh = Wo1hi; dl = Wo1lo;  n4 = 128 * HD / 4;  break;
        case 5:  src = Wo2; dh = Wo2hi; dl = Wo2lo;  n4 = 128 * 128 / 4; break;
        case 6:  src = W1;  dh = W1hi;  dl = W1lo;   n4 = 128 * 128 / 4; break;
        default: src = W2;  dh = W2hi;  dl = W2lo;   n4 = 128 * 128 / 4; break;
    }
    const int i = blockIdx.x * 256 + threadIdx.x;
    if (i < n4) {
        const float4 v = ((const float4*)src)[i];
        ushort4 h, l;
        split2(v.x, h.x, l.x);
        split2(v.y, h.y, l.y);
        split2(v.z, h.z, l.z);
        split2(v.w, h.w, l.w);
        ((ushort4*)dh)[i] = h;
        ((ushort4*)dl)[i] = l;
    }
}

// ---------------------------------------------------------------------------
// K1: R[m][node][c] = agents @ Wm^T via bf16x3 MFMA + per-64-col LN partials.
// Grid (32, 36) x 256 thr. ps layout [3][NN][12][2] (partial {sum, sumsq}).
// ---------------------------------------------------------------------------
__global__ __launch_bounds__(256) void proj_mfma_kernel(
    const ushort* __restrict__ Ahi, const ushort* __restrict__ Alo,
    const ushort* __restrict__ Whi, const ushort* __restrict__ Wlo,
    float* __restrict__ R, float* __restrict__ ps)
{
    const int tid = threadIdx.x;
    const int wave = tid >> 6, lane = tid & 63;
    const int row0 = blockIdx.x * 64 + wave * 16;
    const int cb0  = blockIdx.y * 64;
    const int m0   = blockIdx.y / 12, pb = blockIdx.y % 12;
    const int lrow = lane & 15, kq = lane >> 4;
    const int koff = kq * 8;

    const ushort* ah = Ahi + (size_t)(row0 + lrow) * 128 + koff;
    const ushort* al = Alo + (size_t)(row0 + lrow) * 128 + koff;

    f32x4 acc[4];
    #pragma unroll
    for (int ct = 0; ct < 4; ++ct)
        #pragma unroll
        for (int j = 0; j < 4; ++j) acc[ct][j] = 0.f;

    #pragma unroll
    for (int kt = 0; kt < 4; ++kt) {
        const bf16x8 avh = *(const bf16x8*)(ah + kt * 32);
        const bf16x8 avl = *(const bf16x8*)(al + kt * 32);
        #pragma unroll
        for (int ct = 0; ct < 4; ++ct) {
            const size_t wof = (size_t)(cb0 + ct * 16 + lrow) * 128 + koff + kt * 32;
            const bf16x8 bvh = *(const bf16x8*)(Whi + wof);
            const bf16x8 bvl = *(const bf16x8*)(Wlo + wof);
            acc[ct] = __builtin_amdgcn_mfma_f32_16x16x32_bf16(avh, bvh, acc[ct], 0, 0, 0);
            acc[ct] = __builtin_amdgcn_mfma_f32_16x16x32_bf16(avh, bvl, acc[ct], 0, 0, 0);
            acc[ct] = __builtin_amdgcn_mfma_f32_16x16x32_bf16(avl, bvh, acc[ct], 0, 0, 0);
        }
    }

    // D: col = lane&15, row = (lane>>4)*4 + j
    const int cloc = cb0 - m0 * 768;   // col base within matrix m0
    #pragma unroll
    for (int ct = 0; ct < 4; ++ct) {
        const int c = cloc + ct * 16 + lrow;
        float* rp = R + ((size_t)m0 * NN + row0 + kq * 4) * HD + c;
        #pragma unroll
        for (int j = 0; j < 4; ++j)
            rp[(size_t)j * HD] = acc[ct][j];
    }

    // per-row partial LN stats over this block's 64 cols
    #pragma unroll
    for (int j = 0; j < 4; ++j) {
        float sj = acc[0][j] + acc[1][j] + acc[2][j] + acc[3][j];
        float qj = acc[0][j] * acc[0][j] + acc[1][j] * acc[1][j]
                 + acc[2][j] * acc[2][j] + acc[3][j] * acc[3][j];
        #pragma unroll
        for (int msk = 1; msk <= 8; msk <<= 1) {
            sj += __shfl_xor(sj, msk);
            qj += __shfl_xor(qj, msk);
        }
        if (lrow == 0) {
            const size_t o = ((size_t)m0 * NN + row0 + kq * 4 + j) * 24 + pb * 2;
            ps[o]     = sj;
            ps[o + 1] = qj;
        }
    }
}

// ---------------------------------------------------------------------------
// K2: fused attention + Wo1. Block = (scene, head), 256 thr = 4 waves.
// Waves 0-1: attention for query-tile rt=wave (QK^T, softmax, PV -> ob LDS).
// Then ALL 4 waves split the Wo1 GEMM: wave w = (qtile w&1, colgrp w>>1).
// P layout [6][2048][128] per-head K-split partials (no atomics).
// ---------------------------------------------------------------------------
__global__ __launch_bounds__(256) void attn_wo1_kernel(
    const float* __restrict__ R, const float* __restrict__ ps,
    const float* __restrict__ gq, const float* __restrict__ bq,
    const float* __restrict__ gk, const float* __restrict__ bk,
    const float* __restrict__ gv, const float* __restrict__ bv,
    const ushort* __restrict__ Wo1hi, const ushort* __restrict__ Wo1lo,
    float* __restrict__ P)
{
    __shared__ float stat_s[3][32][2];
    __shared__ ushort phi[2][16][40];
    __shared__ ushort plo[2][16][40];
    __shared__ float ob[2][16][140];   // pitch 140: <=2-way conflicts
    const int tid = threadIdx.x;
    const int wave = tid >> 6, lane = tid & 63;
    const int lrow = lane & 15, kq = lane >> 4;
    const int scene = blockIdx.x, h = blockIdx.y;
    const int brow = scene * 32;

    const float* Rq = R;
    const float* Rk = R + (size_t)NN * HD;
    const float* Rv = R + (size_t)2 * NN * HD;

    // combine 12 LN partials per row into LDS {mu, rstd}
    if (tid < 96) {
        const int m = tid >> 5, row = tid & 31;
        const float4* pv = (const float4*)(ps + ((size_t)m * NN + brow + row) * 24);
        float s = 0.f, q = 0.f;
        #pragma unroll
        for (int c = 0; c < 6; ++c) {
            const float4 v = pv[c];
            s += v.x + v.z;
            q += v.y + v.w;
        }
        const float mu  = s * (1.f / 768.f);
        const float var = q * (1.f / 768.f) - mu * mu;
        stat_s[m][row][0] = mu;
        stat_s[m][row][1] = rsqrtf(var + 1e-5f);
    }
    __syncthreads();

    // ---- attention phase 1: QK^T + softmax (waves 0,1) ----
    if (wave < 2) {
        const int rt = wave;
        const int qrow = brow + rt * 16 + lrow;
        const float muq = stat_s[0][rt * 16 + lrow][0];
        const float rsq = stat_s[0][rt * 16 + lrow][1];
        float muk[2], rsk[2];
        #pragma unroll
        for (int ct = 0; ct < 2; ++ct) {
            muk[ct] = stat_s[1][ct * 16 + lrow][0];
            rsk[ct] = stat_s[1][ct * 16 + lrow][1];
        }

        f32x4 s[2];
        #pragma unroll
        for (int ct = 0; ct < 2; ++ct)
            #pragma unroll
            for (int j = 0; j < 4; ++j) s[ct][j] = 0.f;

        #pragma unroll
        for (int kt = 0; kt < 4; ++kt) {
            const int c0 = h * 128 + kt * 32 + kq * 8;
            bf16x8 qh, ql;
            ln8_split(Rq + (size_t)qrow * HD + c0, muq, rsq, gq + c0, bq + c0, qh, ql);
            #pragma unroll
            for (int ct = 0; ct < 2; ++ct) {
                bf16x8 kh, kl;
                ln8_split(Rk + (size_t)(brow + ct * 16 + lrow) * HD + c0, muk[ct], rsk[ct],
                          gk + c0, bk + c0, kh, kl);
                s[ct] = __builtin_amdgcn_mfma_f32_16x16x32_bf16(qh, kh, s[ct], 0, 0, 0);
                s[ct] = __builtin_amdgcn_mfma_f32_16x16x32_bf16(qh, kl, s[ct], 0, 0, 0);
                s[ct] = __builtin_amdgcn_mfma_f32_16x16x32_bf16(ql, kh, s[ct], 0, 0, 0);
            }
        }

        // row softmax over 32 keys (row = kq*4+j)
        const float scl = 0.08838834764831845f;  // 1/sqrt(128)
        #pragma unroll
        for (int j = 0; j < 4; ++j) {
            const float a = s[0][j] * scl, b = s[1][j] * scl;
            float m = fmaxf(a, b);
            #pragma unroll
            for (int msk = 1; msk <= 8; msk <<= 1) m = fmaxf(m, __shfl_xor(m, msk));
            const float ea = __expf(a - m), eb = __expf(b - m);
            float su = ea + eb;
            #pragma unroll
            for (int msk = 1; msk <= 8; msk <<= 1) su += __shfl_xor(su, msk);
            const float inv = 1.f / su;
            ushort hh, ll;
            split2(ea * inv, hh, ll);
            phi[rt][kq * 4 + j][lrow] = hh;
            plo[rt][kq * 4 + j][lrow] = ll;
            split2(eb * inv, hh, ll);
            phi[rt][kq * 4 + j][16 + lrow] = hh;
            plo[rt][kq * 4 + j][16 + lrow] = ll;
        }
    }
    __syncthreads();

    // ---- attention phase 2: PV -> ob (waves 0,1) ----
    if (wave < 2) {
        const int rt = wave;
        const bf16x8 pah = *(const bf16x8*)&phi[rt][lrow][kq * 8];
        const bf16x8 pal = *(const bf16x8*)&plo[rt][lrow][kq * 8];
        float muv[8], rsv[8];
        #pragma unroll
        for (int j = 0; j < 8; ++j) {
            muv[j] = stat_s[2][kq * 8 + j][0];
            rsv[j] = stat_s[2][kq * 8 + j][1];
        }
        #pragma unroll
        for (int dt = 0; dt < 8; ++dt) {
            const int d = h * 128 + dt * 16 + lrow;
            const float gvd = gv[d], bvd = bv[d];
            ushort vh[8], vl[8];
            #pragma unroll
            for (int j = 0; j < 8; ++j) {
                const float x = Rv[(size_t)(brow + kq * 8 + j) * HD + d];
                const float v = fmaxf((x - muv[j]) * rsv[j] * gvd + bvd, 0.f);
                split2(v, vh[j], vl[j]);
            }
            const bf16x8 bh = pack8(vh), bl = pack8(vl);
            f32x4 o;
            #pragma unroll
            for (int j = 0; j < 4; ++j) o[j] = 0.f;
            o = __builtin_amdgcn_mfma_f32_16x16x32_bf16(pah, bh, o, 0, 0, 0);
            o = __builtin_amdgcn_mfma_f32_16x16x32_bf16(pah, bl, o, 0, 0, 0);
            o = __builtin_amdgcn_mfma_f32_16x16x32_bf16(pal, bh, o, 0, 0, 0);
            #pragma unroll
            for (int j = 0; j < 4; ++j)
                ob[rt][kq * 4 + j][dt * 16 + lrow] = o[j];
        }
    }
    __syncthreads();

    // ---- Wo1 phase: all 4 waves. wave w -> qtile (w&1), colgrp (w>>1) ----
    const int qt = wave & 1, cg = wave >> 1;
    bf16x8 oh[4], ol[4];
    #pragma unroll
    for (int kt = 0; kt < 4; ++kt) {
        const float4 z0 = *(const float4*)&ob[qt][lrow][kt * 32 + kq * 8];
        const float4 z1 = *(const float4*)&ob[qt][lrow][kt * 32 + kq * 8 + 4];
        const float zz[8] = {z0.x, z0.y, z0.z, z0.w, z1.x, z1.y, z1.z, z1.w};
        ushort hh[8], ll[8];
        #pragma unroll
        for (int j = 0; j < 8; ++j) split2(zz[j], hh[j], ll[j]);
        oh[kt] = pack8(hh); ol[kt] = pack8(ll);
    }

    #pragma unroll
    for (int ct2 = 0; ct2 < 4; ++ct2) {
        const int ct = cg * 4 + ct2;
        f32x4 p2;
        #pragma unroll
        for (int j = 0; j < 4; ++j) p2[j] = 0.f;
        const size_t wb = (size_t)(ct * 16 + lrow) * HD + h * 128;
        #pragma unroll
        for (int kt = 0; kt < 4; ++kt) {
            const int c0 = kt * 32 + kq * 8;
            const bf16x8 wh = *(const bf16x8*)(Wo1hi + wb + c0);
            const bf16x8 wl = *(const bf16x8*)(Wo1lo + wb + c0);
            p2 = __builtin_amdgcn_mfma_f32_16x16x32_bf16(oh[kt], wh, p2, 0, 0, 0);
            p2 = __builtin_amdgcn_mfma_f32_16x16x32_bf16(oh[kt], wl, p2, 0, 0, 0);
            p2 = __builtin_amdgcn_mfma_f32_16x16x32_bf16(ol[kt], wh, p2, 0, 0, 0);
        }
        float* pp = P + ((size_t)h * NN + brow + qt * 16 + kq * 4) * 128 + ct * 16 + lrow;
        #pragma unroll
        for (int j = 0; j < 4; ++j)
            pp[(size_t)j * 128] = p2[j];
    }
}

// ---------------------------------------------------------------------------
// K3: fused epilogue, 8 waves / block (512 thr), 16 nodes / block, grid 128.
//  t = relu(LN(sum_h P[h])) in A-frag layout (redundant per wave);
//  u = t@Wo2^T + A@W1^T with wave = col-tile; z = relu(LN(u)) cross-wave;
//  out = relu(z@W2^T + A) with wave = col-tile.
// ---------------------------------------------------------------------------
__global__ __launch_bounds__(512) void epilogue_mfma_kernel(
    const float* __restrict__ P,
    const ushort* __restrict__ Ahi, const ushort* __restrict__ Alo,
    const float* __restrict__ agents,
    const float* __restrict__ go, const float* __restrict__ bo,
    const ushort* __restrict__ Wo2hi, const ushort* __restrict__ Wo2lo,
    const ushort* __restrict__ W1hi, const ushort* __restrict__ W1lo,
    const float* __restrict__ gn, const float* __restrict__ bn,
    const ushort* __restrict__ W2hi, const ushort* __restrict__ W2lo,
    float* __restrict__ out)
{
    __shared__ float zb[16][132];
    __shared__ float red2[8][16][2];
    const int tid = threadIdx.x;
    const int wave = tid >> 6, lane = tid & 63;
    const int lrow = lane & 15, kq = lane >> 4;
    const int n0 = blockIdx.x * 16;
    const int nodeA = n0 + lrow;

    // ---- t = relu(LN(sum_h P[h])), A-frag layout (redundant per wave) ----
    float tv[4][8];
    float s = 0.f, q = 0.f;
    #pragma unroll
    for (int kt = 0; kt < 4; ++kt) {
        const int c0 = kt * 32 + kq * 8;
        const size_t base = (size_t)nodeA * 128 + c0;
        #pragma unroll
        for (int hf = 0; hf < 2; ++hf) {
            float ax = 0.f, ay = 0.f, az = 0.f, aw = 0.f;
            #pragma unroll
            for (int head = 0; head < 6; ++head) {
                const float4 v = *(const float4*)(P + (size_t)head * NN * 128 + base + hf * 4);
                ax += v.x; ay += v.y; az += v.z; aw += v.w;
            }
            tv[kt][hf * 4 + 0] = ax;
            tv[kt][hf * 4 + 1] = ay;
            tv[kt][hf * 4 + 2] = az;
            tv[kt][hf * 4 + 3] = aw;
        }
        #pragma unroll
        for (int j = 0; j < 8; ++j) { s += tv[kt][j]; q += tv[kt][j] * tv[kt][j]; }
    }
    s += __shfl_xor(s, 16); s += __shfl_xor(s, 32);
    q += __shfl_xor(q, 16); q += __shfl_xor(q, 32);
    const float mu = s * (1.f / 128.f);
    const float rs = rsqrtf(q * (1.f / 128.f) - mu * mu + 1e-5f);

    bf16x8 th[4], tl[4], ah[4], al[4];
    #pragma unroll
    for (int kt = 0; kt < 4; ++kt) {
        const int c0 = kt * 32 + kq * 8;
        const float4 g0 = *(const float4*)(go + c0);
        const float4 g1 = *(const float4*)(go + c0 + 4);
        const float4 b0 = *(const float4*)(bo + c0);
        const float4 b1 = *(const float4*)(bo + c0 + 4);
        const float gg[8] = {g0.x, g0.y, g0.z, g0.w, g1.x, g1.y, g1.z, g1.w};
        const float bb[8] = {b0.x, b0.y, b0.z, b0.w, b1.x, b1.y, b1.z, b1.w};
        ushort hh[8], ll[8];
        #pragma unroll
        for (int j = 0; j < 8; ++j) {
            const float v = fmaxf((tv[kt][j] - mu) * rs * gg[j] + bb[j], 0.f);
            split2(v, hh[j], ll[j]);
        }
        th[kt] = pack8(hh); tl[kt] = pack8(ll);
        ah[kt] = *(const bf16x8*)(Ahi + (size_t)nodeA * 128 + c0);
        al[kt] = *(const bf16x8*)(Alo + (size_t)nodeA * 128 + c0);
    }

    // ---- u = t@Wo2^T + A@W1^T  (this wave's single col-tile) ----
    const int ct = wave;
    f32x4 u;
    #pragma unroll
    for (int j = 0; j < 4; ++j) u[j] = 0.f;
    {
        const size_t wb = (size_t)(ct * 16 + lrow) * 128;
        #pragma unroll
        for (int kt = 0; kt < 4; ++kt) {
            const int c0 = kt * 32 + kq * 8;
            const bf16x8 wh = *(const bf16x8*)(Wo2hi + wb + c0);
            const bf16x8 wl = *(const bf16x8*)(Wo2lo + wb + c0);
            const bf16x8 vh = *(const bf16x8*)(W1hi + wb + c0);
            const bf16x8 vl = *(const bf16x8*)(W1lo + wb + c0);
            u = __builtin_amdgcn_mfma_f32_16x16x32_bf16(th[kt], wh, u, 0, 0, 0);
            u = __builtin_amdgcn_mfma_f32_16x16x32_bf16(th[kt], wl, u, 0, 0, 0);
            u = __builtin_amdgcn_mfma_f32_16x16x32_bf16(tl[kt], wh, u, 0, 0, 0);
            u = __builtin_amdgcn_mfma_f32_16x16x32_bf16(ah[kt], vh, u, 0, 0, 0);
            u = __builtin_amdgcn_mfma_f32_16x16x32_bf16(ah[kt], vl, u, 0, 0, 0);
            u = __builtin_amdgcn_mfma_f32_16x16x32_bf16(al[kt], vh, u, 0, 0, 0);
        }
    }

    // ---- z = relu(LN(u)): cross-wave reduction via LDS (8 partials) ----
    #pragma unroll
    for (int j = 0; j < 4; ++j) {
        float s2 = u[j];
        float q2 = u[j] * u[j];
        #pragma unroll
        for (int msk = 1; msk <= 8; msk <<= 1) {
            s2 += __shfl_xor(s2, msk);
            q2 += __shfl_xor(q2, msk);
        }
        if (lrow == 0) {
            red2[wave][kq * 4 + j][0] = s2;
            red2[wave][kq * 4 + j][1] = q2;
        }
    }
    __syncthreads();
    #pragma unroll
    for (int j = 0; j < 4; ++j) {
        const int row = kq * 4 + j;
        float s2t = 0.f, q2t = 0.f;
        #pragma unroll
        for (int w = 0; w < 8; ++w) { s2t += red2[w][row][0]; q2t += red2[w][row][1]; }
        const float mu2 = s2t * (1.f / 128.f);
        const float rs2 = rsqrtf(q2t * (1.f / 128.f) - mu2 * mu2 + 1e-5f);
        const int c = ct * 16 + lrow;
        zb[row][c] = fmaxf((u[j] - mu2) * rs2 * gn[c] + bn[c], 0.f);
    }
    __syncthreads();

    // ---- out = relu(z@W2^T + A)  (this wave's single col-tile) ----
    bf16x8 zh[4], zl[4];
    #pragma unroll
    for (int kt = 0; kt < 4; ++kt) {
        const int c0 = kt * 32 + kq * 8;
        const float4 z0 = *(const float4*)&zb[lrow][c0];
        const float4 z1 = *(const float4*)&zb[lrow][c0 + 4];
        const float zz[8] = {z0.x, z0.y, z0.z, z0.w, z1.x, z1.y, z1.z, z1.w};
        ushort hh[8], ll[8];
        #pragma unroll
        for (int j = 0; j < 8; ++j) split2(zz[j], hh[j], ll[j]);
        zh[kt] = pack8(hh); zl[kt] = pack8(ll);
    }
    {
        f32x4 o;
        #pragma unroll
        for (int j = 0; j < 4; ++j) o[j] = 0.f;
        const size_t wb = (size_t)(ct * 16 + lrow) * 128;
        #pragma unroll
        for (int kt = 0; kt < 4; ++kt) {
            const int c0 = kt * 32 + kq * 8;
            const bf16x8 wh = *(const bf16x8*)(W2hi + wb + c0);
            const bf16x8 wl = *(const bf16x8*)(W2lo + wb + c0);
            o = __builtin_amdgcn_mfma_f32_16x16x32_bf16(zh[kt], wh, o, 0, 0, 0);
            o = __builtin_amdgcn_mfma_f32_16x16x32_bf16(zh[kt], wl, o, 0, 0, 0);
            o = __builtin_amdgcn_mfma_f32_16x16x32_bf16(zl[kt], wh, o, 0, 0, 0);
        }
        #pragma unroll
        for (int j = 0; j < 4; ++j) {
            const size_t oo = (size_t)(n0 + kq * 4 + j) * 128 + ct * 16 + lrow;
            out[oo] = fmaxf(o[j] + agents[oo], 0.f);
        }
    }
}

// ---------------------------------------------------------------------------
extern "C" void kernel_launch(void* const* d_in, const int* in_sizes, int n_in,
                              void* d_out, int out_size, void* d_ws, size_t ws_size,
                              hipStream_t stream) {
    (void)in_sizes; (void)n_in; (void)out_size; (void)ws_size;
    const float* agents = (const float*)d_in[0];
    const float* Wq  = (const float*)d_in[3];
    const float* gq  = (const float*)d_in[4];
    const float* bq  = (const float*)d_in[5];
    const float* Wk  = (const float*)d_in[6];
    const float* gk  = (const float*)d_in[7];
    const float* bk  = (const float*)d_in[8];
    const float* Wv  = (const float*)d_in[9];
    const float* gv  = (const float*)d_in[10];
    const float* bv  = (const float*)d_in[11];
    const float* Wo1 = (const float*)d_in[12];
    const float* go  = (const float*)d_in[13];
    const float* bo  = (const float*)d_in[14];
    const float* Wo2 = (const float*)d_in[15];
    const float* W1  = (const float*)d_in[16];
    const float* gn  = (const float*)d_in[17];
    const float* bn  = (const float*)d_in[18];
    const float* W2  = (const float*)d_in[19];
    float* out = (float*)d_out;

    float* ws = (float*)d_ws;
    float* R  = ws;                                   // 3*NN*HD fp32
    float* Pp = R + (size_t)3 * NN * HD;              // 6*NN*128 fp32
    float* ps = Pp + (size_t)6 * NN * 128;            // 3*NN*24 fp32 partials
    ushort* u = (ushort*)(ps + (size_t)3 * NN * 24);  // 16B-aligned bf16 zone
    ushort* Ahi   = u;  u += (size_t)NN * 128;
    ushort* Alo   = u;  u += (size_t)NN * 128;
    ushort* Whi   = u;  u += (size_t)3 * 768 * 128;
    ushort* Wlo   = u;  u += (size_t)3 * 768 * 128;
    ushort* Wo1hi = u;  u += (size_t)128 * HD;
    ushort* Wo1lo = u;  u += (size_t)128 * HD;
    ushort* Wo2hi = u;  u += (size_t)128 * 128;
    ushort* Wo2lo = u;  u += (size_t)128 * 128;
    ushort* W1hi  = u;  u += (size_t)128 * 128;
    ushort* W1lo  = u;  u += (size_t)128 * 128;
    ushort* W2hi  = u;  u += (size_t)128 * 128;
    ushort* W2lo  = u;  u += (size_t)128 * 128;

    split_kernel<<<dim3(256, 8), 256, 0, stream>>>(
        agents, Wq, Wk, Wv, Wo1, Wo2, W1, W2,
        Ahi, Alo, Whi, Wlo, Wo1hi, Wo1lo, Wo2hi, Wo2lo, W1hi, W1lo, W2hi, W2lo);
    proj_mfma_kernel<<<dim3(32, 36), 256, 0, stream>>>(Ahi, Alo, Whi, Wlo, R, ps);
    attn_wo1_kernel<<<dim3(NB, HH), 256, 0, stream>>>(R, ps, gq, bq, gk, bk, gv, bv,
                                                      Wo1hi, Wo1lo, Pp);
    epilogue_mfma_kernel<<<128, 512, 0, stream>>>(Pp, Ahi, Alo, agents, go, bo,
                                                  Wo2hi, Wo2lo, W1hi, W1lo, gn, bn,
                                                  W2hi, W2lo, out);
}

// Round 13
// 159.250 us; speedup vs baseline: 1.0298x; 1.0298x over previous
//
#include <hip/hip_runtime.h>
#include <math.h>

#define NN 2048      // nodes
#define HH 6         // heads
#define HD 768       // H*D
#define NA 32        // agents/scene
#define NB 64        // scenes

typedef __bf16 bf16x8 __attribute__((ext_vector_type(8)));
typedef float  f32x4  __attribute__((ext_vector_type(4)));

// split f into bf16 hi + bf16 lo (truncation; hi+lo ~ 2^-17 relative)
__device__ __forceinline__ void split2(float f, ushort& h, ushort& l) {
    const uint u = __float_as_uint(f);
    h = (ushort)(u >> 16);
    const float hf = __uint_as_float((uint)h << 16);
    l = (ushort)(__float_as_uint(f - hf) >> 16);
}

__device__ __forceinline__ bf16x8 pack8(const ushort* s) {
    uint4 u;
    u.x = (uint)s[0] | ((uint)s[1] << 16);
    u.y = (uint)s[2] | ((uint)s[3] << 16);
    u.z = (uint)s[4] | ((uint)s[5] << 16);
    u.w = (uint)s[6] | ((uint)s[7] << 16);
    return *(bf16x8*)&u;
}

// load 8 fp32 and split to bf16 hi/lo fragments
__device__ __forceinline__ void f32x8_split(
    const float* __restrict__ x, bf16x8& hi, bf16x8& lo)
{
    const float4 x0 = *(const float4*)x;
    const float4 x1 = *(const float4*)(x + 4);
    const float xv[8] = {x0.x, x0.y, x0.z, x0.w, x1.x, x1.y, x1.z, x1.w};
    ushort hh[8], ll[8];
    #pragma unroll
    for (int j = 0; j < 8; ++j) split2(xv[j], hh[j], ll[j]);
    hi = pack8(hh); lo = pack8(ll);
}

// load 8 fp32, apply LN (gamma/beta), split to bf16 hi/lo fragments
__device__ __forceinline__ void ln8_split(
    const float* __restrict__ x, float mu, float rs,
    const float* __restrict__ g, const float* __restrict__ b,
    bf16x8& hi, bf16x8& lo)
{
    const float4 x0 = *(const float4*)x;
    const float4 x1 = *(const float4*)(x + 4);
    const float4 g0 = *(const float4*)g;
    const float4 g1 = *(const float4*)(g + 4);
    const float4 b0 = *(const float4*)b;
    const float4 b1 = *(const float4*)(b + 4);
    ushort hh[8], ll[8];
    float v;
    v = (x0.x - mu) * rs * g0.x + b0.x; split2(v, hh[0], ll[0]);
    v = (x0.y - mu) * rs * g0.y + b0.y; split2(v, hh[1], ll[1]);
    v = (x0.z - mu) * rs * g0.z + b0.z; split2(v, hh[2], ll[2]);
    v = (x0.w - mu) * rs * g0.w + b0.w; split2(v, hh[3], ll[3]);
    v = (x1.x - mu) * rs * g1.x + b1.x; split2(v, hh[4], ll[4]);
    v = (x1.y - mu) * rs * g1.y + b1.y; split2(v, hh[5], ll[5]);
    v = (x1.z - mu) * rs * g1.z + b1.z; split2(v, hh[6], ll[6]);
    v = (x1.w - mu) * rs * g1.w + b1.w; split2(v, hh[7], ll[7]);
    hi = pack8(hh); lo = pack8(ll);
}

// ---------------------------------------------------------------------------
// K1: R[m][node][c] = agents @ Wm^T via bf16x3 MFMA + per-64-col LN partials.
// Inline fp32->bf16hi/lo split of A and W (no pre-split pass).
// Grid (32, 36) x 256 thr. ps layout [3][NN][12][2] (partial {sum, sumsq}).
// ---------------------------------------------------------------------------
__global__ __launch_bounds__(256) void proj_mfma_kernel(
    const float* __restrict__ A,
    const float* __restrict__ Wq, const float* __restrict__ Wk, const float* __restrict__ Wv,
    float* __restrict__ R, float* __restrict__ ps)
{
    const int tid = threadIdx.x;
    const int wave = tid >> 6, lane = tid & 63;
    const int row0 = blockIdx.x * 64 + wave * 16;
    const int m0   = blockIdx.y / 12, pb = blockIdx.y % 12;
    const int cloc = pb * 64;                  // col base within matrix m0
    const int lrow = lane & 15, kq = lane >> 4;
    const int koff = kq * 8;
    const float* W = (m0 == 0) ? Wq : (m0 == 1) ? Wk : Wv;

    // A fragments (4 k-tiles), split inline
    bf16x8 avh[4], avl[4];
    #pragma unroll
    for (int kt = 0; kt < 4; ++kt)
        f32x8_split(A + (size_t)(row0 + lrow) * 128 + koff + kt * 32, avh[kt], avl[kt]);

    f32x4 acc[4];
    #pragma unroll
    for (int ct = 0; ct < 4; ++ct)
        #pragma unroll
        for (int j = 0; j < 4; ++j) acc[ct][j] = 0.f;

    #pragma unroll
    for (int kt = 0; kt < 4; ++kt) {
        #pragma unroll
        for (int ct = 0; ct < 4; ++ct) {
            bf16x8 bvh, bvl;
            f32x8_split(W + (size_t)(cloc + ct * 16 + lrow) * 128 + koff + kt * 32, bvh, bvl);
            acc[ct] = __builtin_amdgcn_mfma_f32_16x16x32_bf16(avh[kt], bvh, acc[ct], 0, 0, 0);
            acc[ct] = __builtin_amdgcn_mfma_f32_16x16x32_bf16(avh[kt], bvl, acc[ct], 0, 0, 0);
            acc[ct] = __builtin_amdgcn_mfma_f32_16x16x32_bf16(avl[kt], bvh, acc[ct], 0, 0, 0);
        }
    }

    // D: col = lane&15, row = (lane>>4)*4 + j
    #pragma unroll
    for (int ct = 0; ct < 4; ++ct) {
        const int c = cloc + ct * 16 + lrow;
        float* rp = R + ((size_t)m0 * NN + row0 + kq * 4) * HD + c;
        #pragma unroll
        for (int j = 0; j < 4; ++j)
            rp[(size_t)j * HD] = acc[ct][j];
    }

    // per-row partial LN stats over this block's 64 cols
    #pragma unroll
    for (int j = 0; j < 4; ++j) {
        float sj = acc[0][j] + acc[1][j] + acc[2][j] + acc[3][j];
        float qj = acc[0][j] * acc[0][j] + acc[1][j] * acc[1][j]
                 + acc[2][j] * acc[2][j] + acc[3][j] * acc[3][j];
        #pragma unroll
        for (int msk = 1; msk <= 8; msk <<= 1) {
            sj += __shfl_xor(sj, msk);
            qj += __shfl_xor(qj, msk);
        }
        if (lrow == 0) {
            const size_t o = ((size_t)m0 * NN + row0 + kq * 4 + j) * 24 + pb * 2;
            ps[o]     = sj;
            ps[o + 1] = qj;
        }
    }
}

// ---------------------------------------------------------------------------
// K2: fused attention + Wo1 (R11 config: 128 thr, 2 waves). Block=(scene,head).
// Wave rt handles query rows [rt*16, rt*16+16). QK^T -> softmax -> PV keeps
// O in LDS; P_head = O @ Wo1_head^T (fp32 Wo1 split inline) written as
// per-head K-split partials P[6][2048][128] (no atomics).
// ---------------------------------------------------------------------------
__global__ __launch_bounds__(128) void attn_wo1_kernel(
    const float* __restrict__ R, const float* __restrict__ ps,
    const float* __restrict__ gq, const float* __restrict__ bq,
    const float* __restrict__ gk, const float* __restrict__ bk,
    const float* __restrict__ gv, const float* __restrict__ bv,
    const float* __restrict__ Wo1,
    float* __restrict__ P)
{
    __shared__ float stat_s[3][32][2];
    __shared__ ushort phi[2][16][40];
    __shared__ ushort plo[2][16][40];
    __shared__ float ob[2][16][140];   // pitch 140: <=2-way conflicts
    const int tid = threadIdx.x;
    const int rt = tid >> 6, lane = tid & 63;
    const int lrow = lane & 15, kq = lane >> 4;
    const int scene = blockIdx.x, h = blockIdx.y;
    const int brow = scene * 32;

    const float* Rq = R;
    const float* Rk = R + (size_t)NN * HD;
    const float* Rv = R + (size_t)2 * NN * HD;

    // combine 12 LN partials per row into LDS {mu, rstd}
    if (tid < 96) {
        const int m = tid >> 5, row = tid & 31;
        const float4* pv = (const float4*)(ps + ((size_t)m * NN + brow + row) * 24);
        float s = 0.f, q = 0.f;
        #pragma unroll
        for (int c = 0; c < 6; ++c) {
            const float4 v = pv[c];
            s += v.x + v.z;
            q += v.y + v.w;
        }
        const float mu  = s * (1.f / 768.f);
        const float var = q * (1.f / 768.f) - mu * mu;
        stat_s[m][row][0] = mu;
        stat_s[m][row][1] = rsqrtf(var + 1e-5f);
    }
    __syncthreads();

    const int qrow = brow + rt * 16 + lrow;
    const float muq = stat_s[0][rt * 16 + lrow][0];
    const float rsq = stat_s[0][rt * 16 + lrow][1];
    float muk[2], rsk[2];
    #pragma unroll
    for (int ct = 0; ct < 2; ++ct) {
        muk[ct] = stat_s[1][ct * 16 + lrow][0];
        rsk[ct] = stat_s[1][ct * 16 + lrow][1];
    }
    float muv[8], rsv[8];
    #pragma unroll
    for (int j = 0; j < 8; ++j) {
        muv[j] = stat_s[2][kq * 8 + j][0];
        rsv[j] = stat_s[2][kq * 8 + j][1];
    }

    // S = Q K^T (16 queries x 32 keys), LN fused into fragment builds
    f32x4 s[2];
    #pragma unroll
    for (int ct = 0; ct < 2; ++ct)
        #pragma unroll
        for (int j = 0; j < 4; ++j) s[ct][j] = 0.f;

    #pragma unroll
    for (int kt = 0; kt < 4; ++kt) {
        const int c0 = h * 128 + kt * 32 + kq * 8;
        bf16x8 qh, ql;
        ln8_split(Rq + (size_t)qrow * HD + c0, muq, rsq, gq + c0, bq + c0, qh, ql);
        #pragma unroll
        for (int ct = 0; ct < 2; ++ct) {
            bf16x8 kh, kl;
            ln8_split(Rk + (size_t)(brow + ct * 16 + lrow) * HD + c0, muk[ct], rsk[ct],
                      gk + c0, bk + c0, kh, kl);
            s[ct] = __builtin_amdgcn_mfma_f32_16x16x32_bf16(qh, kh, s[ct], 0, 0, 0);
            s[ct] = __builtin_amdgcn_mfma_f32_16x16x32_bf16(qh, kl, s[ct], 0, 0, 0);
            s[ct] = __builtin_amdgcn_mfma_f32_16x16x32_bf16(ql, kh, s[ct], 0, 0, 0);
        }
    }

    // row softmax over 32 keys (row = kq*4+j; cols spread over lrow x 2 ct)
    const float scl = 0.08838834764831845f;  // 1/sqrt(128)
    float p0[4], p1[4];
    #pragma unroll
    for (int j = 0; j < 4; ++j) {
        const float a = s[0][j] * scl, b = s[1][j] * scl;
        float m = fmaxf(a, b);
        #pragma unroll
        for (int msk = 1; msk <= 8; msk <<= 1) m = fmaxf(m, __shfl_xor(m, msk));
        const float ea = __expf(a - m), eb = __expf(b - m);
        float su = ea + eb;
        #pragma unroll
        for (int msk = 1; msk <= 8; msk <<= 1) su += __shfl_xor(su, msk);
        const float inv = 1.f / su;
        p0[j] = ea * inv;
        p1[j] = eb * inv;
    }

    // transpose P-attn to A-frag layout via LDS (per-wave buffer)
    #pragma unroll
    for (int j = 0; j < 4; ++j) {
        ushort hh, ll;
        split2(p0[j], hh, ll);
        phi[rt][kq * 4 + j][lrow] = hh;
        plo[rt][kq * 4 + j][lrow] = ll;
        split2(p1[j], hh, ll);
        phi[rt][kq * 4 + j][16 + lrow] = hh;
        plo[rt][kq * 4 + j][16 + lrow] = ll;
    }
    __syncthreads();
    const bf16x8 pah = *(const bf16x8*)&phi[rt][lrow][kq * 8];
    const bf16x8 pal = *(const bf16x8*)&plo[rt][lrow][kq * 8];

    // O = P V over 8 d-tiles; LN+relu on V fused into B-frag build
    f32x4 o[8];
    #pragma unroll
    for (int dt = 0; dt < 8; ++dt) {
        const int d = h * 128 + dt * 16 + lrow;
        const float gvd = gv[d], bvd = bv[d];
        ushort vh[8], vl[8];
        #pragma unroll
        for (int j = 0; j < 8; ++j) {
            const float x = Rv[(size_t)(brow + kq * 8 + j) * HD + d];
            const float v = fmaxf((x - muv[j]) * rsv[j] * gvd + bvd, 0.f);
            split2(v, vh[j], vl[j]);
        }
        const bf16x8 bh = pack8(vh), bl = pack8(vl);
        #pragma unroll
        for (int j = 0; j < 4; ++j) o[dt][j] = 0.f;
        o[dt] = __builtin_amdgcn_mfma_f32_16x16x32_bf16(pah, bh, o[dt], 0, 0, 0);
        o[dt] = __builtin_amdgcn_mfma_f32_16x16x32_bf16(pah, bl, o[dt], 0, 0, 0);
        o[dt] = __builtin_amdgcn_mfma_f32_16x16x32_bf16(pal, bh, o[dt], 0, 0, 0);
    }

    // transpose O (C-layout: row=kq*4+j, col=dt*16+lrow) to A-frag via LDS
    #pragma unroll
    for (int dt = 0; dt < 8; ++dt)
        #pragma unroll
        for (int j = 0; j < 4; ++j)
            ob[rt][kq * 4 + j][dt * 16 + lrow] = o[dt][j];
    __syncthreads();

    bf16x8 oh[4], ol[4];
    #pragma unroll
    for (int kt = 0; kt < 4; ++kt) {
        const float4 z0 = *(const float4*)&ob[rt][lrow][kt * 32 + kq * 8];
        const float4 z1 = *(const float4*)&ob[rt][lrow][kt * 32 + kq * 8 + 4];
        const float zz[8] = {z0.x, z0.y, z0.z, z0.w, z1.x, z1.y, z1.z, z1.w};
        ushort hh[8], ll[8];
        #pragma unroll
        for (int j = 0; j < 8; ++j) split2(zz[j], hh[j], ll[j]);
        oh[kt] = pack8(hh); ol[kt] = pack8(ll);
    }

    // P_head = O @ Wo1[:, h*128:+128]^T  (fp32 Wo1, split inline)
    #pragma unroll
    for (int ct = 0; ct < 8; ++ct) {
        f32x4 p2;
        #pragma unroll
        for (int j = 0; j < 4; ++j) p2[j] = 0.f;
        const size_t wb = (size_t)(ct * 16 + lrow) * HD + h * 128;
        #pragma unroll
        for (int kt = 0; kt < 4; ++kt) {
            bf16x8 wh, wl;
            f32x8_split(Wo1 + wb + kt * 32 + kq * 8, wh, wl);
            p2 = __builtin_amdgcn_mfma_f32_16x16x32_bf16(oh[kt], wh, p2, 0, 0, 0);
            p2 = __builtin_amdgcn_mfma_f32_16x16x32_bf16(oh[kt], wl, p2, 0, 0, 0);
            p2 = __builtin_amdgcn_mfma_f32_16x16x32_bf16(ol[kt], wh, p2, 0, 0, 0);
        }
        float* pp = P + ((size_t)h * NN + brow + rt * 16 + kq * 4) * 128 + ct * 16 + lrow;
        #pragma unroll
        for (int j = 0; j < 4; ++j)
            pp[(size_t)j * 128] = p2[j];
    }
}

// ---------------------------------------------------------------------------
// K3: fused epilogue (R11 config: 4 waves / block, 16 nodes, grid 128).
//  t = relu(LN(sum_h P[h])) in A-frag layout; u = t@Wo2^T + A@W1^T;
//  z = relu(LN(u)) cross-wave; out = relu(z@W2^T + A). fp32 weights split
//  inline; A fragments from fp32 agents.
// ---------------------------------------------------------------------------
__global__ __launch_bounds__(256) void epilogue_mfma_kernel(
    const float* __restrict__ P,
    const float* __restrict__ agents,
    const float* __restrict__ go, const float* __restrict__ bo,
    const float* __restrict__ Wo2, const float* __restrict__ W1,
    const float* __restrict__ gn, const float* __restrict__ bn,
    const float* __restrict__ W2,
    float* __restrict__ out)
{
    __shared__ float zb[16][132];
    __shared__ float red2[4][16][2];
    const int tid = threadIdx.x;
    const int wave = tid >> 6, lane = tid & 63;
    const int lrow = lane & 15, kq = lane >> 4;
    const int n0 = blockIdx.x * 16;
    const int nodeA = n0 + lrow;

    // ---- t = relu(LN(sum_h P[h])), A-frag layout (redundant per wave) ----
    float tv[4][8];
    float s = 0.f, q = 0.f;
    #pragma unroll
    for (int kt = 0; kt < 4; ++kt) {
        const int c0 = kt * 32 + kq * 8;
        const size_t base = (size_t)nodeA * 128 + c0;
        #pragma unroll
        for (int hf = 0; hf < 2; ++hf) {
            float ax = 0.f, ay = 0.f, az = 0.f, aw = 0.f;
            #pragma unroll
            for (int head = 0; head < 6; ++head) {
                const float4 v = *(const float4*)(P + (size_t)head * NN * 128 + base + hf * 4);
                ax += v.x; ay += v.y; az += v.z; aw += v.w;
            }
            tv[kt][hf * 4 + 0] = ax;
            tv[kt][hf * 4 + 1] = ay;
            tv[kt][hf * 4 + 2] = az;
            tv[kt][hf * 4 + 3] = aw;
        }
        #pragma unroll
        for (int j = 0; j < 8; ++j) { s += tv[kt][j]; q += tv[kt][j] * tv[kt][j]; }
    }
    s += __shfl_xor(s, 16); s += __shfl_xor(s, 32);
    q += __shfl_xor(q, 16); q += __shfl_xor(q, 32);
    const float mu = s * (1.f / 128.f);
    const float rs = rsqrtf(q * (1.f / 128.f) - mu * mu + 1e-5f);

    bf16x8 th[4], tl[4], ah[4], al[4];
    #pragma unroll
    for (int kt = 0; kt < 4; ++kt) {
        const int c0 = kt * 32 + kq * 8;
        const float4 g0 = *(const float4*)(go + c0);
        const float4 g1 = *(const float4*)(go + c0 + 4);
        const float4 b0 = *(const float4*)(bo + c0);
        const float4 b1 = *(const float4*)(bo + c0 + 4);
        const float gg[8] = {g0.x, g0.y, g0.z, g0.w, g1.x, g1.y, g1.z, g1.w};
        const float bb[8] = {b0.x, b0.y, b0.z, b0.w, b1.x, b1.y, b1.z, b1.w};
        ushort hh[8], ll[8];
        #pragma unroll
        for (int j = 0; j < 8; ++j) {
            const float v = fmaxf((tv[kt][j] - mu) * rs * gg[j] + bb[j], 0.f);
            split2(v, hh[j], ll[j]);
        }
        th[kt] = pack8(hh); tl[kt] = pack8(ll);
        f32x8_split(agents + (size_t)nodeA * 128 + c0, ah[kt], al[kt]);
    }

    // ---- u = t@Wo2^T + A@W1^T  (this wave's 2 col-tiles) ----
    f32x4 u[2];
    #pragma unroll
    for (int ct2 = 0; ct2 < 2; ++ct2)
        #pragma unroll
        for (int j = 0; j < 4; ++j) u[ct2][j] = 0.f;

    #pragma unroll
    for (int ct2 = 0; ct2 < 2; ++ct2) {
        const int ct = wave * 2 + ct2;
        const size_t wb = (size_t)(ct * 16 + lrow) * 128;
        #pragma unroll
        for (int kt = 0; kt < 4; ++kt) {
            const int c0 = kt * 32 + kq * 8;
            bf16x8 wh, wl, vh, vl;
            f32x8_split(Wo2 + wb + c0, wh, wl);
            f32x8_split(W1 + wb + c0, vh, vl);
            u[ct2] = __builtin_amdgcn_mfma_f32_16x16x32_bf16(th[kt], wh, u[ct2], 0, 0, 0);
            u[ct2] = __builtin_amdgcn_mfma_f32_16x16x32_bf16(th[kt], wl, u[ct2], 0, 0, 0);
            u[ct2] = __builtin_amdgcn_mfma_f32_16x16x32_bf16(tl[kt], wh, u[ct2], 0, 0, 0);
            u[ct2] = __builtin_amdgcn_mfma_f32_16x16x32_bf16(ah[kt], vh, u[ct2], 0, 0, 0);
            u[ct2] = __builtin_amdgcn_mfma_f32_16x16x32_bf16(ah[kt], vl, u[ct2], 0, 0, 0);
            u[ct2] = __builtin_amdgcn_mfma_f32_16x16x32_bf16(al[kt], vh, u[ct2], 0, 0, 0);
        }
    }

    // ---- z = relu(LN(u)): cross-wave reduction via LDS ----
    #pragma unroll
    for (int j = 0; j < 4; ++j) {
        float s2 = u[0][j] + u[1][j];
        float q2 = u[0][j] * u[0][j] + u[1][j] * u[1][j];
        #pragma unroll
        for (int msk = 1; msk <= 8; msk <<= 1) {
            s2 += __shfl_xor(s2, msk);
            q2 += __shfl_xor(q2, msk);
        }
        if (lrow == 0) {
            red2[wave][kq * 4 + j][0] = s2;
            red2[wave][kq * 4 + j][1] = q2;
        }
    }
    __syncthreads();
    #pragma unroll
    for (int j = 0; j < 4; ++j) {
        const int row = kq * 4 + j;
        const float s2t = red2[0][row][0] + red2[1][row][0] + red2[2][row][0] + red2[3][row][0];
        const float q2t = red2[0][row][1] + red2[1][row][1] + red2[2][row][1] + red2[3][row][1];
        const float mu2 = s2t * (1.f / 128.f);
        const float rs2 = rsqrtf(q2t * (1.f / 128.f) - mu2 * mu2 + 1e-5f);
        #pragma unroll
        for (int ct2 = 0; ct2 < 2; ++ct2) {
            const int c = (wave * 2 + ct2) * 16 + lrow;
            zb[row][c] = fmaxf((u[ct2][j] - mu2) * rs2 * gn[c] + bn[c], 0.f);
        }
    }
    __syncthreads();

    // ---- out = relu(z@W2^T + A)  (this wave's 2 col-tiles) ----
    bf16x8 zh[4], zl[4];
    #pragma unroll
    for (int kt = 0; kt < 4; ++kt) {
        const int c0 = kt * 32 + kq * 8;
        const float4 z0 = *(const float4*)&zb[lrow][c0];
        const float4 z1 = *(const float4*)&zb[lrow][c0 + 4];
        const float zz[8] = {z0.x, z0.y, z0.z, z0.w, z1.x, z1.y, z1.z, z1.w};
        ushort hh[8], ll[8];
        #pragma unroll
        for (int j = 0; j < 8; ++j) split2(zz[j], hh[j], ll[j]);
        zh[kt] = pack8(hh); zl[kt] = pack8(ll);
    }
    #pragma unroll
    for (int ct2 = 0; ct2 < 2; ++ct2) {
        const int ct = wave * 2 + ct2;
        f32x4 o;
        #pragma unroll
        for (int j = 0; j < 4; ++j) o[j] = 0.f;
        const size_t wb = (size_t)(ct * 16 + lrow) * 128;
        #pragma unroll
        for (int kt = 0; kt < 4; ++kt) {
            const int c0 = kt * 32 + kq * 8;
            bf16x8 wh, wl;
            f32x8_split(W2 + wb + c0, wh, wl);
            o = __builtin_amdgcn_mfma_f32_16x16x32_bf16(zh[kt], wh, o, 0, 0, 0);
            o = __builtin_amdgcn_mfma_f32_16x16x32_bf16(zh[kt], wl, o, 0, 0, 0);
            o = __builtin_amdgcn_mfma_f32_16x16x32_bf16(zl[kt], wh, o, 0, 0, 0);
        }
        #pragma unroll
        for (int j = 0; j < 4; ++j) {
            const size_t oo = (size_t)(n0 + kq * 4 + j) * 128 + ct * 16 + lrow;
            out[oo] = fmaxf(o[j] + agents[oo], 0.f);
        }
    }
}

// ---------------------------------------------------------------------------
extern "C" void kernel_launch(void* const* d_in, const int* in_sizes, int n_in,
                              void* d_out, int out_size, void* d_ws, size_t ws_size,
                              hipStream_t stream) {
    (void)in_sizes; (void)n_in; (void)out_size; (void)ws_size;
    const float* agents = (const float*)d_in[0];
    const float* Wq  = (const float*)d_in[3];
    const float* gq  = (const float*)d_in[4];
    const float* bq  = (const float*)d_in[5];
    const float* Wk  = (const float*)d_in[6];
    const float* gk  = (const float*)d_in[7];
    const float* bk  = (const float*)d_in[8];
    const float* Wv  = (const float*)d_in[9];
    const float* gv  = (const float*)d_in[10];
    const float* bv  = (const float*)d_in[11];
    const float* Wo1 = (const float*)d_in[12];
    const float* go  = (const float*)d_in[13];
    const float* bo  = (const float*)d_in[14];
    const float* Wo2 = (const float*)d_in[15];
    const float* W1  = (const float*)d_in[16];
    const float* gn  = (const float*)d_in[17];
    const float* bn  = (const float*)d_in[18];
    const float* W2  = (const float*)d_in[19];
    float* out = (float*)d_out;

    float* ws = (float*)d_ws;
    float* R  = ws;                                   // 3*NN*HD fp32
    float* Pp = R + (size_t)3 * NN * HD;              // 6*NN*128 fp32
    float* ps = Pp + (size_t)6 * NN * 128;            // 3*NN*24 fp32 partials

    proj_mfma_kernel<<<dim3(32, 36), 256, 0, stream>>>(agents, Wq, Wk, Wv, R, ps);
    attn_wo1_kernel<<<dim3(NB, HH), 128, 0, stream>>>(R, ps, gq, bq, gk, bk, gv, bv,
                                                      Wo1, Pp);
    epilogue_mfma_kernel<<<128, 256, 0, stream>>>(Pp, agents, go, bo, Wo2, W1,
                                                  gn, bn, W2, out);
}